// Round 9
// baseline (135.765 us; speedup 1.0000x reference)
//
#include <hip/hip_runtime.h>
#include <hip/hip_bf16.h>
#include <stdint.h>

#define N 8192
#define D 512
#define TILE 128
#define NTB (N / TILE)                // 64 tile-rows (= #slices)
#define NBLK (NTB * (NTB + 1) / 2)    // 2080 upper-tri blocks
#define PANEL_BYTES (TILE * D)        // 65536 B per 128-row fp8 panel

typedef long long i64;
typedef __attribute__((ext_vector_type(4))) float f32x4;

// Fn2 swizzled fp8 layout (R7, verified):
//   byte(p, kb, q, lr) = p*65536 + kb*4096 + q*1024 + lr*8
// (kb = 0..15 counts 32-wide k-chunks; q = k-octet within chunk; lr = row 0..127)
// values = fp8_e4m3(16 * normalized_row)
// -> MFMA fragment (rows rb*16..+15, k-chunk kb) for lane (q,n15) is the i64 at
//    q*1024 + (row)*8 + kb*4096: per-quad 16 lanes read 128 contiguous bytes.
__global__ void cc_normalize(const float* __restrict__ F, uint8_t* __restrict__ Fn2,
                             float* __restrict__ out) {
    if (blockIdx.x == 0 && threadIdx.x == 0) out[0] = 0.0f;
    const int row  = blockIdx.x * 4 + (threadIdx.x >> 6);
    const int lane = threadIdx.x & 63;
    const float* p = F + (size_t)row * D + lane * 8;
    float4 a = *(const float4*)p;
    float4 b = *(const float4*)(p + 4);
    float ss = a.x*a.x + a.y*a.y + a.z*a.z + a.w*a.w
             + b.x*b.x + b.y*b.y + b.z*b.z + b.w*b.w;
    #pragma unroll
    for (int m = 32; m; m >>= 1) ss += __shfl_xor(ss, m, 64);
    const float inv = 16.0f / fmaxf(sqrtf(ss), 1e-12f);
    int lo = 0, hi = 0;
    lo = __builtin_amdgcn_cvt_pk_fp8_f32(a.x*inv, a.y*inv, lo, false);
    lo = __builtin_amdgcn_cvt_pk_fp8_f32(a.z*inv, a.w*inv, lo, true);
    hi = __builtin_amdgcn_cvt_pk_fp8_f32(b.x*inv, b.y*inv, hi, false);
    hi = __builtin_amdgcn_cvt_pk_fp8_f32(b.z*inv, b.w*inv, hi, true);
    const size_t idx = (size_t)(row >> 7) * PANEL_BYTES + (size_t)lane * 1024 + (row & 127) * 8;
    *(int2*)(Fn2 + idx) = make_int2(lo, hi);
}

// Barrier-free K-loop: MFMA fragments loaded directly from the swizzled
// global panels (L2-hot, coalesced). No LDS staging, no fences, no atomics.
// Block (bm,bn) writes row-sums to slice bn and col-sums to slice bm (R6 scheme).
__global__ __launch_bounds__(256, 4)
void cc_gemm(const uint8_t* __restrict__ Fn2, const int* __restrict__ cl,
             float* __restrict__ Pt, float* __restrict__ Pp) {
    __shared__ int crow[TILE], ccol[TILE];
    __shared__ float rsum[2][TILE][2];   // [wc][row][te,tp]
    __shared__ float csum[2][TILE][2];   // [wr][col][te,tp]

    const int tid  = threadIdx.x;
    const int wave = tid >> 6;
    const int lane = tid & 63;

    // natural upper-tri decode (R7 ordering — best measured L2 behavior)
    int rem = blockIdx.x, bm = 0;
    while (rem >= NTB - bm) { rem -= NTB - bm; ++bm; }
    const int bn = bm + rem;
    const bool diag = (bm == bn);

    if (tid < TILE)            crow[tid]        = cl[bm * TILE + tid];
    else                       ccol[tid - TILE] = cl[bn * TILE + (tid - TILE)];

    const int wr = wave >> 1, wc = wave & 1;    // 2x2 wave grid, 64x64 each
    const int q   = lane >> 4;
    const int n15 = lane & 15;

    f32x4 acc[4][4];
    #pragma unroll
    for (int t = 0; t < 4; ++t)
        #pragma unroll
        for (int u = 0; u < 4; ++u) acc[t][u] = (f32x4)(0.0f);

    // per-fragment global base pointers (lane-resolved); advance 4096 B per kb
    const uint8_t* pa[4];
    const uint8_t* pb[4];
    #pragma unroll
    for (int t = 0; t < 4; ++t)
        pa[t] = Fn2 + (size_t)bm * PANEL_BYTES + q * 1024 + (wr * 64 + t * 16 + n15) * 8;
    #pragma unroll
    for (int u = 0; u < 4; ++u)
        pb[u] = Fn2 + (size_t)bn * PANEL_BYTES + q * 1024 + (wc * 64 + u * 16 + n15) * 8;

    __syncthreads();   // crow/ccol visible (only pre-epilogue barrier)

    #pragma unroll 4
    for (int kb = 0; kb < 16; ++kb) {
        i64 af[4], bfr[4];
        #pragma unroll
        for (int t = 0; t < 4; ++t)
            af[t] = *(const i64*)(pa[t] + (size_t)kb * 4096);
        #pragma unroll
        for (int u = 0; u < 4; ++u)
            bfr[u] = *(const i64*)(pb[u] + (size_t)kb * 4096);
        #pragma unroll
        for (int t = 0; t < 4; ++t)
            #pragma unroll
            for (int u = 0; u < 4; ++u)
                acc[t][u] = __builtin_amdgcn_mfma_f32_16x16x32_fp8_fp8(af[t], bfr[u], acc[t][u], 0, 0, 0);
    }

    // epilogue: sim = dot/256; e = exp2(dot * 10*log2(e)/256)
    // C layout col=lane&15, row=q*4+reg
    const float SC = 0.05635527503472514f;
    int cc[4];
    #pragma unroll
    for (int u = 0; u < 4; ++u) cc[u] = ccol[wc * 64 + u * 16 + n15];

    float ce[4] = {0.f, 0.f, 0.f, 0.f};
    float cp[4] = {0.f, 0.f, 0.f, 0.f};

    #pragma unroll
    for (int t = 0; t < 4; ++t) {
        #pragma unroll
        for (int r = 0; r < 4; ++r) {
            const int lr  = wr * 64 + t * 16 + q * 4 + r;
            const int myc = crow[lr];
            float te = 0.0f, tp = 0.0f;
            #pragma unroll
            for (int u = 0; u < 4; ++u) {
                const float e  = exp2f(acc[t][u][r] * SC);
                const float ep = (cc[u] == myc) ? e : 0.0f;
                te += e;  tp += ep;
                ce[u] += e;  cp[u] += ep;
            }
            #pragma unroll
            for (int m = 1; m < 16; m <<= 1) {
                te += __shfl_xor(te, m, 64);
                tp += __shfl_xor(tp, m, 64);
            }
            if (n15 == 0) { rsum[wc][lr][0] = te; rsum[wc][lr][1] = tp; }
        }
    }

    if (!diag) {
        #pragma unroll
        for (int u = 0; u < 4; ++u) {
            float e = ce[u], p2 = cp[u];
            e += __shfl_xor(e, 16, 64);  p2 += __shfl_xor(p2, 16, 64);
            e += __shfl_xor(e, 32, 64);  p2 += __shfl_xor(p2, 32, 64);
            if (lane < 16) {
                const int lc = wc * 64 + u * 16 + n15;
                csum[wr][lc][0] = e;  csum[wr][lc][1] = p2;
            }
        }
    }

    __syncthreads();
    if (tid < TILE) {
        const float te = rsum[0][tid][0] + rsum[1][tid][0];
        const float tp = rsum[0][tid][1] + rsum[1][tid][1];
        const size_t o = (size_t)bn * N + bm * TILE + tid;
        Pt[o] = te;  Pp[o] = tp;
    } else if (!diag) {
        const int c = tid - TILE;
        const float te = csum[0][c][0] + csum[1][c][0];
        const float tp = csum[0][c][1] + csum[1][c][1];
        const size_t o = (size_t)bm * N + bn * TILE + c;
        Pt[o] = te;  Pp[o] = tp;
    }
}

// 32 blocks x 256: row i sums its 64 slices, loss, block-reduce, atomicAdd out
__global__ void cc_finalize(const float* __restrict__ Pt, const float* __restrict__ Pp,
                            float* __restrict__ out) {
    __shared__ float red[4];
    const int i = blockIdx.x * 256 + threadIdx.x;
    float tv = 0.0f, pv = 0.0f;
    #pragma unroll 8
    for (int s = 0; s < NTB; ++s) {
        tv += Pt[(size_t)s * N + i];
        pv += Pp[(size_t)s * N + i];
    }
    float l = __logf(tv + 1e-8f) - __logf(pv);
    #pragma unroll
    for (int m = 32; m; m >>= 1) l += __shfl_xor(l, m, 64);
    const int wv = threadIdx.x >> 6, lane = threadIdx.x & 63;
    if (lane == 0) red[wv] = l;
    __syncthreads();
    if (threadIdx.x == 0) atomicAdd(out, red[0] + red[1] + red[2] + red[3]);
}

extern "C" void kernel_launch(void* const* d_in, const int* in_sizes, int n_in,
                              void* d_out, int out_size, void* d_ws, size_t ws_size,
                              hipStream_t stream) {
    const float* F  = (const float*)d_in[0];
    const int*   cl = (const int*)d_in[1];
    float* out = (float*)d_out;

    uint8_t* Fn2 = (uint8_t*)d_ws;                               // 4 MB fp8 swizzled
    float* Pt  = (float*)((char*)d_ws + (size_t)N * D);          // 2 MB
    float* Pp  = Pt + (size_t)NTB * N;                           // 2 MB

    cc_normalize<<<N / 4, 256, 0, stream>>>(F, Fn2, out);
    cc_gemm<<<NBLK, 256, 0, stream>>>(Fn2, cl, Pt, Pp);
    cc_finalize<<<N / 256, 256, 0, stream>>>(Pt, Pp, out);
}

// Round 10
// 134.199 us; speedup vs baseline: 1.0117x; 1.0117x over previous
//
#include <hip/hip_runtime.h>
#include <hip/hip_bf16.h>
#include <stdint.h>

#define N 8192
#define D 512
#define TILE 128
#define BK 64
#define NKC (D / BK)                  // 8 K-chunks
#define NTB (N / TILE)                // 64 tile-rows (= #slices)
#define NBLK (NTB * (NTB + 1) / 2)    // 2080 upper-tri blocks
#define PANEL_BYTES (TILE * D)        // 65536 B per 128-row fp8 panel
#define KCHUNK_BYTES (TILE * BK)      // 8192 B per staged fp8 tile

typedef long long i64;
typedef unsigned long long u64;
typedef __attribute__((ext_vector_type(4))) float f32x4;

// async global->LDS, 16B per lane; LDS dest = wave-uniform base + lane*16
__device__ __forceinline__ void gload_lds16(const void* gp, const void* lp) {
    auto g = (const __attribute__((address_space(1))) void*)(uintptr_t)gp;
    auto l = (__attribute__((address_space(3))) void*)(uintptr_t)lp;
    __builtin_amdgcn_global_load_lds(g, l, 16, 0, 0);
}

__device__ __forceinline__ u64 pack2(float a, float b) {
    union { float2 f; u64 u; } v; v.f = make_float2(a, b); return v.u;
}

// Fn2 swizzled fp8 layout (R7, verified):
//   byte(p, kc, ks, q, lr) = p*65536 + kc*8192 + ks*4096 + q*1024 + lr*8
// values = fp8_e4m3(16 * normalized_row)
__global__ void cc_normalize(const float* __restrict__ F, uint8_t* __restrict__ Fn2,
                             int* __restrict__ tcnt, float* __restrict__ out) {
    if (blockIdx.x == 0) {
        if (threadIdx.x == 0) out[0] = 0.0f;
        if (threadIdx.x < NTB) tcnt[threadIdx.x] = 0;
    }
    const int row  = blockIdx.x * 4 + (threadIdx.x >> 6);
    const int lane = threadIdx.x & 63;
    const float* p = F + (size_t)row * D + lane * 8;
    float4 a = *(const float4*)p;
    float4 b = *(const float4*)(p + 4);
    float ss = a.x*a.x + a.y*a.y + a.z*a.z + a.w*a.w
             + b.x*b.x + b.y*b.y + b.z*b.z + b.w*b.w;
    #pragma unroll
    for (int m = 32; m; m >>= 1) ss += __shfl_xor(ss, m, 64);
    const float inv = 16.0f / fmaxf(sqrtf(ss), 1e-12f);
    int lo = 0, hi = 0;
    lo = __builtin_amdgcn_cvt_pk_fp8_f32(a.x*inv, a.y*inv, lo, false);
    lo = __builtin_amdgcn_cvt_pk_fp8_f32(a.z*inv, a.w*inv, lo, true);
    hi = __builtin_amdgcn_cvt_pk_fp8_f32(b.x*inv, b.y*inv, hi, false);
    hi = __builtin_amdgcn_cvt_pk_fp8_f32(b.z*inv, b.w*inv, hi, true);
    const size_t idx = (size_t)(row >> 7) * PANEL_BYTES + (size_t)lane * 1024 + (row & 127) * 8;
    *(int2*)(Fn2 + idx) = make_int2(lo, hi);
}

// R7 K-loop (LDS double-buffer, single barrier per step, fp8 MFMA) + fused
// distributed finalize. Partial sums stored as relaxed AGENT-scope atomic
// 8B stores (packed {te,tp}) -> coherent without fences/invalidates. Tile t
// has exactly 64 contributors; the 64th reduces its slices and adds to out.
__global__ __launch_bounds__(256, 4)
void cc_gemm(const uint8_t* __restrict__ Fn2, const int* __restrict__ cl,
             u64* __restrict__ P8, int* __restrict__ tcnt, float* __restrict__ out) {
    __shared__ __align__(16) uint8_t As[2][KCHUNK_BYTES];   // 2 x 8 KB
    __shared__ __align__(16) uint8_t Bs[2][KCHUNK_BYTES];   // 2 x 8 KB
    __shared__ int crow[TILE], ccol[TILE];
    __shared__ float rsum[2][TILE][2];   // [wc][row][te,tp]
    __shared__ float csum[2][TILE][2];   // [wr][col][te,tp]
    __shared__ float red[4];
    __shared__ int fin0, fin1;

    const int tid  = threadIdx.x;
    const int wave = tid >> 6;
    const int lane = tid & 63;

    int rem = blockIdx.x, bm = 0;
    while (rem >= NTB - bm) { rem -= NTB - bm; ++bm; }
    const int bn = bm + rem;
    const bool diag = (bm == bn);

    if (tid < TILE)            crow[tid]        = cl[bm * TILE + tid];
    else                       ccol[tid - TILE] = cl[bn * TILE + (tid - TILE)];

    const int wr = wave >> 1, wc = wave & 1;    // 2x2 wave grid, 64x64 each
    const int q   = lane >> 4;
    const int n15 = lane & 15;

    f32x4 acc[4][4];
    #pragma unroll
    for (int t = 0; t < 4; ++t)
        #pragma unroll
        for (int u = 0; u < 4; ++u) acc[t][u] = (f32x4)(0.0f);

    const uint8_t* Ag = Fn2 + (size_t)bm * PANEL_BYTES;
    const uint8_t* Bg = Fn2 + (size_t)bn * PANEL_BYTES;

    #pragma unroll
    for (int i = 0; i < 2; ++i) {
        const int off = (wave * 2 + i) * 1024;
        gload_lds16(Ag + off + lane * 16, &As[0][off]);
        gload_lds16(Bg + off + lane * 16, &Bs[0][off]);
    }

    for (int kc = 0; kc < NKC; ++kc) {
        const int b = kc & 1;
        __syncthreads();   // drains own vmcnt (stage issued one full phase ago)
        if (kc + 1 < NKC) {
            const uint8_t* ga = Ag + (kc + 1) * KCHUNK_BYTES;
            const uint8_t* gb = Bg + (kc + 1) * KCHUNK_BYTES;
            #pragma unroll
            for (int i = 0; i < 2; ++i) {
                const int off = (wave * 2 + i) * 1024;
                gload_lds16(ga + off + lane * 16, &As[b ^ 1][off]);
                gload_lds16(gb + off + lane * 16, &Bs[b ^ 1][off]);
            }
        }
        #pragma unroll
        for (int ks = 0; ks < 2; ++ks) {
            const int base = ks * 4096 + q * 1024 + n15 * 8;
            i64 af[4], bfr[4];
            #pragma unroll
            for (int t = 0; t < 4; ++t)
                af[t] = *(const i64*)&As[b][base + (wr * 64 + t * 16) * 8];
            #pragma unroll
            for (int u = 0; u < 4; ++u)
                bfr[u] = *(const i64*)&Bs[b][base + (wc * 64 + u * 16) * 8];
            #pragma unroll
            for (int t = 0; t < 4; ++t)
                #pragma unroll
                for (int u = 0; u < 4; ++u)
                    acc[t][u] = __builtin_amdgcn_mfma_f32_16x16x32_fp8_fp8(af[t], bfr[u], acc[t][u], 0, 0, 0);
        }
    }

    // epilogue: sim = dot/256; e = exp2(dot * 10*log2(e)/256)
    const float SC = 0.05635527503472514f;
    int cc[4];
    #pragma unroll
    for (int u = 0; u < 4; ++u) cc[u] = ccol[wc * 64 + u * 16 + n15];

    float ce[4] = {0.f, 0.f, 0.f, 0.f};
    float cp[4] = {0.f, 0.f, 0.f, 0.f};

    #pragma unroll
    for (int t = 0; t < 4; ++t) {
        #pragma unroll
        for (int r = 0; r < 4; ++r) {
            const int lr  = wr * 64 + t * 16 + q * 4 + r;
            const int myc = crow[lr];
            float te = 0.0f, tp = 0.0f;
            #pragma unroll
            for (int u = 0; u < 4; ++u) {
                const float e  = exp2f(acc[t][u][r] * SC);
                const float ep = (cc[u] == myc) ? e : 0.0f;
                te += e;  tp += ep;
                ce[u] += e;  cp[u] += ep;
            }
            #pragma unroll
            for (int m = 1; m < 16; m <<= 1) {
                te += __shfl_xor(te, m, 64);
                tp += __shfl_xor(tp, m, 64);
            }
            if (n15 == 0) { rsum[wc][lr][0] = te; rsum[wc][lr][1] = tp; }
        }
    }

    if (!diag) {
        #pragma unroll
        for (int u = 0; u < 4; ++u) {
            float e = ce[u], p2 = cp[u];
            e += __shfl_xor(e, 16, 64);  p2 += __shfl_xor(p2, 16, 64);
            e += __shfl_xor(e, 32, 64);  p2 += __shfl_xor(p2, 32, 64);
            if (lane < 16) {
                const int lc = wc * 64 + u * 16 + n15;
                csum[wr][lc][0] = e;  csum[wr][lc][1] = p2;
            }
        }
    }

    __syncthreads();
    // coherent (agent-scope) packed stores: no fence/flush needed for visibility
    if (tid < TILE) {
        const u64 v = pack2(rsum[0][tid][0] + rsum[1][tid][0],
                            rsum[0][tid][1] + rsum[1][tid][1]);
        __hip_atomic_store(&P8[(size_t)bn * N + bm * TILE + tid], v,
                           __ATOMIC_RELAXED, __HIP_MEMORY_SCOPE_AGENT);
    } else if (!diag) {
        const int c = tid - TILE;
        const u64 v = pack2(csum[0][c][0] + csum[1][c][0],
                            csum[0][c][1] + csum[1][c][1]);
        __hip_atomic_store(&P8[(size_t)bm * N + bn * TILE + c], v,
                           __ATOMIC_RELAXED, __HIP_MEMORY_SCOPE_AGENT);
    }
    __syncthreads();   // drains vmcnt: all block's coherent stores complete

    if (tid == 0) {
        fin0 = (__hip_atomic_fetch_add(&tcnt[bm], 1, __ATOMIC_RELAXED,
                                       __HIP_MEMORY_SCOPE_AGENT) == NTB - 1);
        fin1 = diag ? 0
             : (__hip_atomic_fetch_add(&tcnt[bn], 1, __ATOMIC_RELAXED,
                                       __HIP_MEMORY_SCOPE_AGENT) == NTB - 1);
    }
    __syncthreads();

    // distributed finalize: 64th contributor of tile t reduces its slices
    #pragma unroll
    for (int pass = 0; pass < 2; ++pass) {
        const bool doit = pass == 0 ? (fin0 != 0) : (fin1 != 0);   // block-uniform
        if (!doit) continue;
        const int t = pass == 0 ? bm : bn;
        const int j = tid & 127, h = tid >> 7;   // h: slice half 0/1
        float tv = 0.f, pv = 0.f;
        const u64* base = P8 + (size_t)(h * 32) * N + t * TILE + j;
        #pragma unroll 8
        for (int s = 0; s < 32; ++s) {
            union { u64 u; float2 f; } w;
            w.u = __hip_atomic_load(base + (size_t)s * N,
                                    __ATOMIC_RELAXED, __HIP_MEMORY_SCOPE_AGENT);
            tv += w.f.x;  pv += w.f.y;
        }
        rsum[h][j][0] = tv;  rsum[h][j][1] = pv;
        __syncthreads();
        float l = 0.0f;
        if (tid < TILE) {
            const float T  = rsum[0][tid][0] + rsum[1][tid][0];
            const float Pv = rsum[0][tid][1] + rsum[1][tid][1];
            l = __logf(T + 1e-8f) - __logf(Pv);
        }
        #pragma unroll
        for (int m = 32; m; m >>= 1) l += __shfl_xor(l, m, 64);
        if (lane == 0) red[wave] = l;
        __syncthreads();
        if (tid == 0) atomicAdd(out, red[0] + red[1] + red[2] + red[3]);
        __syncthreads();   // rsum reused if both passes fire
    }
}

extern "C" void kernel_launch(void* const* d_in, const int* in_sizes, int n_in,
                              void* d_out, int out_size, void* d_ws, size_t ws_size,
                              hipStream_t stream) {
    const float* F  = (const float*)d_in[0];
    const int*   cl = (const int*)d_in[1];
    float* out = (float*)d_out;

    uint8_t* Fn2 = (uint8_t*)d_ws;                               // 4 MB fp8 swizzled
    u64*   P8   = (u64*)((char*)d_ws + (size_t)N * D);           // 64*8192*8 B = 4 MB
    int*   tcnt = (int*)((char*)d_ws + (size_t)N * D + (size_t)NTB * N * 8);  // 256 B

    cc_normalize<<<N / 4, 256, 0, stream>>>(F, Fn2, tcnt, out);
    cc_gemm<<<NBLK, 256, 0, stream>>>(Fn2, cl, P8, tcnt, out);
}

// Round 12
// 124.968 us; speedup vs baseline: 1.0864x; 1.0739x over previous
//
#include <hip/hip_runtime.h>
#include <hip/hip_bf16.h>
#include <stdint.h>

#define N 8192
#define D 512
#define TILE 128
#define BK 64
#define NKC (D / BK)                  // 8 K-chunks
#define NTB (N / TILE)                // 64 tile-rows (= #slices)
#define NBLK (NTB * (NTB + 1) / 2)    // 2080 upper-tri blocks
#define PANEL_BYTES (TILE * D)        // 65536 B per 128-row fp8 panel
#define KCHUNK_BYTES (TILE * BK)      // 8192 B per staged fp8 tile

typedef long long i64;
typedef __attribute__((ext_vector_type(4))) float f32x4;

// async global->LDS, 16B per lane; LDS dest = wave-uniform base + lane*16
__device__ __forceinline__ void gload_lds16(const void* gp, const void* lp) {
    auto g = (const __attribute__((address_space(1))) void*)(uintptr_t)gp;
    auto l = (__attribute__((address_space(3))) void*)(uintptr_t)lp;
    __builtin_amdgcn_global_load_lds(g, l, 16, 0, 0);
}

// Fn2 swizzled fp8 layout (R7, verified):
//   byte(p, kc, ks, q, lr) = p*65536 + kc*8192 + ks*4096 + q*1024 + lr*8
// values = fp8_e4m3(16 * normalized_row)
__global__ void cc_normalize(const float* __restrict__ F, uint8_t* __restrict__ Fn2,
                             float* __restrict__ out) {
    if (blockIdx.x == 0 && threadIdx.x == 0) out[0] = 0.0f;
    const int row  = blockIdx.x * 4 + (threadIdx.x >> 6);
    const int lane = threadIdx.x & 63;
    const float* p = F + (size_t)row * D + lane * 8;
    float4 a = *(const float4*)p;
    float4 b = *(const float4*)(p + 4);
    float ss = a.x*a.x + a.y*a.y + a.z*a.z + a.w*a.w
             + b.x*b.x + b.y*b.y + b.z*b.z + b.w*b.w;
    #pragma unroll
    for (int m = 32; m; m >>= 1) ss += __shfl_xor(ss, m, 64);
    const float inv = 16.0f / fmaxf(sqrtf(ss), 1e-12f);
    int lo = 0, hi = 0;
    lo = __builtin_amdgcn_cvt_pk_fp8_f32(a.x*inv, a.y*inv, lo, false);
    lo = __builtin_amdgcn_cvt_pk_fp8_f32(a.z*inv, a.w*inv, lo, true);
    hi = __builtin_amdgcn_cvt_pk_fp8_f32(b.x*inv, b.y*inv, hi, false);
    hi = __builtin_amdgcn_cvt_pk_fp8_f32(b.z*inv, b.w*inv, hi, true);
    const size_t idx = (size_t)(row >> 7) * PANEL_BYTES + (size_t)lane * 1024 + (row & 127) * 8;
    *(int2*)(Fn2 + idx) = make_int2(lo, hi);
}

// R7 upper-tri fp8 GEMM, but: TRIPLE-buffered LDS, prefetch distance 2,
// and raw `s_waitcnt vmcnt(4); s_barrier` in the K-loop so the newest stage
// stays in flight across the barrier (AITER-style, never vmcnt(0) mid-loop).
// No atomics / no fences; block (bm,bn) writes row sums -> slice bn,
// col sums -> slice bm (R6 disjoint-writer scheme).
__global__ __launch_bounds__(256, 3)
void cc_gemm(const uint8_t* __restrict__ Fn2, const int* __restrict__ cl,
             float* __restrict__ Pt, float* __restrict__ Pp) {
    __shared__ __align__(16) uint8_t smem[6 * KCHUNK_BYTES];   // As[3] | Bs[3], 48 KB
    __shared__ int crow[TILE], ccol[TILE];
    uint8_t* As = smem;
    uint8_t* Bs = smem + 3 * KCHUNK_BYTES;
    // epilogue scratch aliases buffer 0 (last consumed at kc=6; all lgkm
    // drained at the kc=7 barrier, so no live data remains there)
    float (*rsum)[TILE][2] = (float (*)[TILE][2])(smem);          // 2 KB
    float (*csum)[TILE][2] = (float (*)[TILE][2])(smem + 4096);   // 2 KB

    const int tid  = threadIdx.x;
    const int wave = tid >> 6;
    const int lane = tid & 63;

    int rem = blockIdx.x, bm = 0;
    while (rem >= NTB - bm) { rem -= NTB - bm; ++bm; }
    const int bn = bm + rem;
    const bool diag = (bm == bn);

    if (tid < TILE)            crow[tid]        = cl[bm * TILE + tid];
    else                       ccol[tid - TILE] = cl[bn * TILE + (tid - TILE)];

    const int wr = wave >> 1, wc = wave & 1;    // 2x2 wave grid, 64x64 each
    const int q   = lane >> 4;
    const int n15 = lane & 15;

    f32x4 acc[4][4];
    #pragma unroll
    for (int t = 0; t < 4; ++t)
        #pragma unroll
        for (int u = 0; u < 4; ++u) acc[t][u] = (f32x4)(0.0f);

    const uint8_t* Ag = Fn2 + (size_t)bm * PANEL_BYTES;
    const uint8_t* Bg = Fn2 + (size_t)bn * PANEL_BYTES;

    // stage chunk kc into buffer `buf`: 2+2 linear 1KB pieces per wave
    auto stage = [&](int kc, int buf) {
        const uint8_t* ga = Ag + kc * KCHUNK_BYTES;
        const uint8_t* gb = Bg + kc * KCHUNK_BYTES;
        #pragma unroll
        for (int i = 0; i < 2; ++i) {
            const int off = (wave * 2 + i) * 1024;
            gload_lds16(ga + off + lane * 16, As + buf * KCHUNK_BYTES + off);
            gload_lds16(gb + off + lane * 16, Bs + buf * KCHUNK_BYTES + off);
        }
    };

    stage(0, 0);   // prologue: distance-2 pipeline
    stage(1, 1);

    #pragma unroll
    for (int kc = 0; kc < NKC; ++kc) {
        const int b = kc % 3;
        // wait only for loads OLDER than the newest stage (4 loads/wave/stage);
        // the just-issued prefetch stays in flight across the barrier.
        if (kc < NKC - 1)
            asm volatile("s_waitcnt vmcnt(4) lgkmcnt(0)\n\ts_barrier" ::: "memory");
        else
            asm volatile("s_waitcnt vmcnt(0) lgkmcnt(0)\n\ts_barrier" ::: "memory");
        if (kc + 2 < NKC) stage(kc + 2, (kc + 2) % 3);
        #pragma unroll
        for (int ks = 0; ks < 2; ++ks) {
            const int base = b * KCHUNK_BYTES + ks * 4096 + q * 1024 + n15 * 8;
            i64 af[4], bfr[4];
            #pragma unroll
            for (int t = 0; t < 4; ++t)
                af[t] = *(const i64*)&As[base + (wr * 64 + t * 16) * 8];
            #pragma unroll
            for (int u = 0; u < 4; ++u)
                bfr[u] = *(const i64*)&Bs[base + (wc * 64 + u * 16) * 8];
            #pragma unroll
            for (int t = 0; t < 4; ++t)
                #pragma unroll
                for (int u = 0; u < 4; ++u)
                    acc[t][u] = __builtin_amdgcn_mfma_f32_16x16x32_fp8_fp8(af[t], bfr[u], acc[t][u], 0, 0, 0);
        }
    }

    __syncthreads();   // all waves done with LDS buffers; safe to alias rsum/csum

    // epilogue: sim = dot/256; e = exp2(dot * 10*log2(e)/256)
    // C layout col=lane&15, row=q*4+reg
    const float SC = 0.05635527503472514f;
    int cc[4];
    #pragma unroll
    for (int u = 0; u < 4; ++u) cc[u] = ccol[wc * 64 + u * 16 + n15];

    float ce[4] = {0.f, 0.f, 0.f, 0.f};
    float cp[4] = {0.f, 0.f, 0.f, 0.f};

    #pragma unroll
    for (int t = 0; t < 4; ++t) {
        #pragma unroll
        for (int r = 0; r < 4; ++r) {
            const int lr  = wr * 64 + t * 16 + q * 4 + r;
            const int myc = crow[lr];
            float te = 0.0f, tp = 0.0f;
            #pragma unroll
            for (int u = 0; u < 4; ++u) {
                const float e  = exp2f(acc[t][u][r] * SC);
                const float ep = (cc[u] == myc) ? e : 0.0f;
                te += e;  tp += ep;
                ce[u] += e;  cp[u] += ep;
            }
            #pragma unroll
            for (int m = 1; m < 16; m <<= 1) {
                te += __shfl_xor(te, m, 64);
                tp += __shfl_xor(tp, m, 64);
            }
            if (n15 == 0) { rsum[wc][lr][0] = te; rsum[wc][lr][1] = tp; }
        }
    }

    if (!diag) {
        #pragma unroll
        for (int u = 0; u < 4; ++u) {
            float e = ce[u], p2 = cp[u];
            e += __shfl_xor(e, 16, 64);  p2 += __shfl_xor(p2, 16, 64);
            e += __shfl_xor(e, 32, 64);  p2 += __shfl_xor(p2, 32, 64);
            if (lane < 16) {
                const int lc = wc * 64 + u * 16 + n15;
                csum[wr][lc][0] = e;  csum[wr][lc][1] = p2;
            }
        }
    }

    __syncthreads();
    if (tid < TILE) {
        const float te = rsum[0][tid][0] + rsum[1][tid][0];
        const float tp = rsum[0][tid][1] + rsum[1][tid][1];
        const size_t o = (size_t)bn * N + bm * TILE + tid;
        Pt[o] = te;  Pp[o] = tp;
    } else if (!diag) {
        const int c = tid - TILE;
        const float te = csum[0][c][0] + csum[1][c][0];
        const float tp = csum[0][c][1] + csum[1][c][1];
        const size_t o = (size_t)bm * N + bn * TILE + c;
        Pt[o] = te;  Pp[o] = tp;
    }
}

// 32 blocks x 256: row i sums its 64 slices, loss, block-reduce, atomicAdd out
__global__ void cc_finalize(const float* __restrict__ Pt, const float* __restrict__ Pp,
                            float* __restrict__ out) {
    __shared__ float red[4];
    const int i = blockIdx.x * 256 + threadIdx.x;
    float tv = 0.0f, pv = 0.0f;
    #pragma unroll 8
    for (int s = 0; s < NTB; ++s) {
        tv += Pt[(size_t)s * N + i];
        pv += Pp[(size_t)s * N + i];
    }
    float l = __logf(tv + 1e-8f) - __logf(pv);
    #pragma unroll
    for (int m = 32; m; m >>= 1) l += __shfl_xor(l, m, 64);
    const int wv = threadIdx.x >> 6, lane = threadIdx.x & 63;
    if (lane == 0) red[wv] = l;
    __syncthreads();
    if (threadIdx.x == 0) atomicAdd(out, red[0] + red[1] + red[2] + red[3]);
}

extern "C" void kernel_launch(void* const* d_in, const int* in_sizes, int n_in,
                              void* d_out, int out_size, void* d_ws, size_t ws_size,
                              hipStream_t stream) {
    const float* F  = (const float*)d_in[0];
    const int*   cl = (const int*)d_in[1];
    float* out = (float*)d_out;

    uint8_t* Fn2 = (uint8_t*)d_ws;                               // 4 MB fp8 swizzled
    float* Pt  = (float*)((char*)d_ws + (size_t)N * D);          // 2 MB
    float* Pp  = Pt + (size_t)NTB * N;                           // 2 MB

    cc_normalize<<<N / 4, 256, 0, stream>>>(F, Fn2, out);
    cc_gemm<<<NBLK, 256, 0, stream>>>(Fn2, cl, Pt, Pp);
    cc_finalize<<<N / 256, 256, 0, stream>>>(Pt, Pp, out);
}